// Round 13
// baseline (86.605 us; speedup 1.0000x reference)
//
#include <hip/hip_runtime.h>
#include <math.h>

#define NROWS 8192
#define DDIM  64
#define JSPLIT 32
#define JSPAN  (NROWS / JSPLIT)   // 256
#define LOG2E  1.4426950408889634f
#define SKIP_THR (-28.0f)         // exp2(-28)*8192 = 3e-5 on a sum >= 1
#define APAD  72                  // LDS row stride in bf16: 144B -> bank-group uniform

typedef __bf16 bf16x8 __attribute__((ext_vector_type(8)));
typedef float  f32x4  __attribute__((ext_vector_type(4)));

// ws layout (floats): [0,512) mse_part | [512,8704) sum_s | [8704,16896) hp2 |
//   ebf @ 16896 floats (bf16) | ebl after

// ---- k1: convert | MSE partials | hp2 diag-MFMA | zero sum_s ----
__global__ __launch_bounds__(256)
void prep_kernel(const float* __restrict__ yt, const float* __restrict__ yp,
                 const float* __restrict__ enc,
                 __bf16* __restrict__ ebf, __bf16* __restrict__ ebl,
                 float* __restrict__ hp2, float* __restrict__ mse_part,
                 float* __restrict__ sum_s) {
    int bid = blockIdx.x;
    int t   = threadIdx.x;
    if (bid < 256) {
        int off = bid * 2048 + t * 8;
        const float4* e4 = (const float4*)(enc + off);
        float4 x = e4[0], y = e4[1];
        bf16x8 v, w;
        v[0]=(__bf16)x.x; v[1]=(__bf16)x.y; v[2]=(__bf16)x.z; v[3]=(__bf16)x.w;
        v[4]=(__bf16)y.x; v[5]=(__bf16)y.y; v[6]=(__bf16)y.z; v[7]=(__bf16)y.w;
        w[0]=(__bf16)(x.x*LOG2E); w[1]=(__bf16)(x.y*LOG2E);
        w[2]=(__bf16)(x.z*LOG2E); w[3]=(__bf16)(x.w*LOG2E);
        w[4]=(__bf16)(y.x*LOG2E); w[5]=(__bf16)(y.y*LOG2E);
        w[6]=(__bf16)(y.z*LOG2E); w[7]=(__bf16)(y.w*LOG2E);
        *(bf16x8*)(ebf + off) = v;
        *(bf16x8*)(ebl + off) = w;
    } else if (bid < 768) {
        int idx = (bid - 256) * 256 + t;
        const float4* t4 = (const float4*)yt;
        const float4* p4 = (const float4*)yp;
        float4 a = t4[idx], b = p4[idx];
        float dx=b.x-a.x, dy=b.y-a.y, dz=b.z-a.z, dw=b.w-a.w;
        float s = dx*dx + dy*dy + dz*dz + dw*dw;
        #pragma unroll
        for (int off = 32; off > 0; off >>= 1) s += __shfl_down(s, off, 64);
        __shared__ float ls[4];
        int lane = t & 63, w = t >> 6;
        if (lane == 0) ls[w] = s;
        __syncthreads();
        if (t == 0) mse_part[bid - 256] = ls[0] + ls[1] + ls[2] + ls[3];
    } else if (bid < 896) {
        // hp2 from diagonal tile: plain(A) x scaled(B) MFMA, same math as pairwise
        int wv = t >> 6, ln = t & 63;
        int tile = (bid - 768) * 4 + wv;           // 0..511
        int lm = ln & 15, lk = ln >> 4;
        const float* r = enc + (tile * 16 + lm) * DDIM;
        bf16x8 f0, f1, g0, g1;
        {
            const float4* q = (const float4*)(r + lk * 8);
            float4 x = q[0], y = q[1];
            f0[0]=(__bf16)x.x; f0[1]=(__bf16)x.y; f0[2]=(__bf16)x.z; f0[3]=(__bf16)x.w;
            f0[4]=(__bf16)y.x; f0[5]=(__bf16)y.y; f0[6]=(__bf16)y.z; f0[7]=(__bf16)y.w;
            g0[0]=(__bf16)(x.x*LOG2E); g0[1]=(__bf16)(x.y*LOG2E);
            g0[2]=(__bf16)(x.z*LOG2E); g0[3]=(__bf16)(x.w*LOG2E);
            g0[4]=(__bf16)(y.x*LOG2E); g0[5]=(__bf16)(y.y*LOG2E);
            g0[6]=(__bf16)(y.z*LOG2E); g0[7]=(__bf16)(y.w*LOG2E);
        }
        {
            const float4* q = (const float4*)(r + 32 + lk * 8);
            float4 x = q[0], y = q[1];
            f1[0]=(__bf16)x.x; f1[1]=(__bf16)x.y; f1[2]=(__bf16)x.z; f1[3]=(__bf16)x.w;
            f1[4]=(__bf16)y.x; f1[5]=(__bf16)y.y; f1[6]=(__bf16)y.z; f1[7]=(__bf16)y.w;
            g1[0]=(__bf16)(x.x*LOG2E); g1[1]=(__bf16)(x.y*LOG2E);
            g1[2]=(__bf16)(x.z*LOG2E); g1[3]=(__bf16)(x.w*LOG2E);
            g1[4]=(__bf16)(y.x*LOG2E); g1[5]=(__bf16)(y.y*LOG2E);
            g1[6]=(__bf16)(y.z*LOG2E); g1[7]=(__bf16)(y.w*LOG2E);
        }
        f32x4 acc = {0.f, 0.f, 0.f, 0.f};
        acc = __builtin_amdgcn_mfma_f32_16x16x32_bf16(f0, g0, acc, 0, 0, 0);
        acc = __builtin_amdgcn_mfma_f32_16x16x32_bf16(f1, g1, acc, 0, 0, 0);
        #pragma unroll
        for (int reg = 0; reg < 4; ++reg) {
            int rc = lk * 4 + reg;
            if (lm == rc) hp2[tile * 16 + rc] = 0.5f * acc[reg];
        }
    } else {
        int off = (bid - 896) * 2048 + t * 8;
        float4 z = make_float4(0.f, 0.f, 0.f, 0.f);
        ((float4*)(sum_s + off))[0] = z;
        ((float4*)(sum_s + off))[1] = z;
    }
}

// ---- k2: A-strip in LDS; j-unrolled x2 (32 j per A-fragment read) ----
__global__ __launch_bounds__(256)
__attribute__((amdgpu_waves_per_eu(4, 8)))   // <=128 VGPR: keep 16 waves/CU with 38KB LDS
void pairwise_kernel(const __bf16* __restrict__ ebf, const __bf16* __restrict__ ebl,
                     const float* __restrict__ hp2, float* __restrict__ sum_s) {
    __shared__ __bf16 alds[256 * APAD];   // 36864 B
    __shared__ float  hlds[256];

    int t  = threadIdx.x;
    int wv = t >> 6, ln = t & 63;
    int lm = ln & 15, lk = ln >> 4;
    int I0B = blockIdx.x * 256;           // block's row strip
    int j0  = blockIdx.y * JSPAN;

    // stage 256 A-rows + h once per block (one row per thread)
    {
        const bf16x8* src = (const bf16x8*)(ebf + (I0B + t) * DDIM);
        bf16x8* dst = (bf16x8*)(alds + t * APAD);
        #pragma unroll
        for (int k = 0; k < 8; ++k) dst[k] = src[k];
        hlds[t] = hp2[I0B + t];
    }
    __syncthreads();

    float eacc[16];
    #pragma unroll
    for (int i = 0; i < 16; ++i) eacc[i] = 0.f;

    for (int js = 0; js < JSPAN; js += 32) {
        int Jt = j0 + js;
        // two B-tile pairs (32 j's) per A-fragment read
        const __bf16* rp = ebl + (Jt + lm) * DDIM + lk * 8;
        const __bf16* rq = ebl + (Jt + 16 + lm) * DDIM + lk * 8;
        bf16x8 b0 = *(const bf16x8*)(rp);
        bf16x8 b1 = *(const bf16x8*)(rp + 32);
        bf16x8 c0 = *(const bf16x8*)(rq);
        bf16x8 c1 = *(const bf16x8*)(rq + 32);
        float  nhj = -hp2[Jt + lm];
        float  nhk = -hp2[Jt + 16 + lm];

        #pragma unroll
        for (int mt = 0; mt < 4; ++mt) {
            int arow = wv * 64 + mt * 16 + lm;
            const bf16x8* ap = (const bf16x8*)(alds + arow * APAD);
            bf16x8 a0 = ap[lk];           // ds_read_b128
            bf16x8 a1 = ap[4 + lk];       // ds_read_b128
            const f32x4 hv = *(const f32x4*)(hlds + wv * 64 + mt * 16 + lk * 4); // broadcast

            f32x4 acc1 = {nhj - hv[0], nhj - hv[1], nhj - hv[2], nhj - hv[3]};
            acc1 = __builtin_amdgcn_mfma_f32_16x16x32_bf16(a0, b0, acc1, 0, 0, 0);
            acc1 = __builtin_amdgcn_mfma_f32_16x16x32_bf16(a1, b1, acc1, 0, 0, 0);
            f32x4 acc2 = {nhk - hv[0], nhk - hv[1], nhk - hv[2], nhk - hv[3]};
            acc2 = __builtin_amdgcn_mfma_f32_16x16x32_bf16(a0, c0, acc2, 0, 0, 0);
            acc2 = __builtin_amdgcn_mfma_f32_16x16x32_bf16(a1, c1, acc2, 0, 0, 0);

            float m1 = fmaxf(fmaxf(acc1[0], acc1[1]), fmaxf(acc1[2], acc1[3]));
            if (__any(m1 > SKIP_THR)) {
                #pragma unroll
                for (int reg = 0; reg < 4; ++reg)
                    eacc[mt * 4 + reg] += __builtin_amdgcn_exp2f(acc1[reg]);
            }
            float m2 = fmaxf(fmaxf(acc2[0], acc2[1]), fmaxf(acc2[2], acc2[3]));
            if (__any(m2 > SKIP_THR)) {
                #pragma unroll
                for (int reg = 0; reg < 4; ++reg)
                    eacc[mt * 4 + reg] += __builtin_amdgcn_exp2f(acc2[reg]);
            }
        }
    }
    #pragma unroll
    for (int i = 0; i < 16; ++i) {
        float v = eacc[i];
        v += __shfl_xor(v, 1, 64);
        v += __shfl_xor(v, 2, 64);
        v += __shfl_xor(v, 4, 64);
        v += __shfl_xor(v, 8, 64);
        if (lm == 0) {
            int mt = i >> 2, reg = i & 3;
            atomicAdd(&sum_s[I0B + wv * 64 + mt * 16 + lk * 4 + reg], v);
        }
    }
}

// ---- k3: finalize (log-mean + mse partial sum + outputs) ----
__global__ __launch_bounds__(1024)
void finalize_kernel(const float* __restrict__ sum_s,
                     const float* __restrict__ mse_part,
                     float* __restrict__ out) {
    int t = threadIdx.x, lane = t & 63, w = t >> 6;
    float s = 0.0f;
    #pragma unroll
    for (int u = 0; u < 8; ++u) s += __logf(sum_s[t * 8 + u]);
    float m = (t < 512) ? mse_part[t] : 0.f;
    #pragma unroll
    for (int off = 32; off > 0; off >>= 1) {
        s += __shfl_down(s, off, 64);
        m += __shfl_down(m, off, 64);
    }
    __shared__ float rs[16], rm[16];
    if (lane == 0) { rs[w] = s; rm[w] = m; }
    __syncthreads();
    if (t == 0) {
        float tot = 0.f, mtot = 0.f;
        #pragma unroll
        for (int i = 0; i < 16; ++i) { tot += rs[i]; mtot += rm[i]; }
        float kde = tot / (float)NROWS;
        float c   = logf((float)NROWS);
        float IXT = (c - kde) / logf(2.0f);
        float mse = mtot / (float)(NROWS * DDIM);
        out[0] = 1.0f * IXT + 500.0f * mse;
        out[1] = IXT;
        out[2] = mse;
    }
}

extern "C" void kernel_launch(void* const* d_in, const int* in_sizes, int n_in,
                              void* d_out, int out_size, void* d_ws, size_t ws_size,
                              hipStream_t stream) {
    const float* y_true  = (const float*)d_in[0];
    const float* y_pred  = (const float*)d_in[1];
    const float* encoded = (const float*)d_in[2];
    float* out = (float*)d_out;

    float*  wsf      = (float*)d_ws;
    float*  mse_part = wsf;                        // 512
    float*  sum_s    = wsf + 512;                  // 8192
    float*  hp2      = wsf + 512 + NROWS;          // 8192
    __bf16* ebf      = (__bf16*)(wsf + 512 + 2 * NROWS);
    __bf16* ebl      = ebf + NROWS * DDIM;

    prep_kernel<<<900, 256, 0, stream>>>(y_true, y_pred, encoded,
                                         ebf, ebl, hp2, mse_part, sum_s);
    pairwise_kernel<<<dim3(NROWS / 256, JSPLIT), 256, 0, stream>>>(ebf, ebl, hp2, sum_s);
    finalize_kernel<<<1, 1024, 0, stream>>>(sum_s, mse_part, out);
}